// Round 8
// baseline (298.748 us; speedup 1.0000x reference)
//
#include <hip/hip_runtime.h>

// ---------------------------------------------------------------------------
// HeteroGNN, round 8: XCD-local histogram atomics.
//   out = relu( [mean_i | mean_t | x_user] @ [Wl_i; Wl_t; W_user@(Wr_i+Wr_t)]
//               + (b_user@(Wr_i+Wr_t) + bl_i + bl_t) )        [MFMA, K=512]
// CSR: per-XCD histogram copies (HW_REG_XCC_ID) + workgroup-scope L2-local
// atomics; rank = local_rank | (xcc<<28); merge -> per-copy offsets + totals
// (fused with scan pass 1); atomic-free scatter. Gather: 16 lanes/node bf16.
// MFMA 16x16x32_bf16: A row=lane&15, k=(lane>>4)*8+j; B col=lane&15;
// D col=lane&15, row=(lane>>4)*4+reg  [m89-verified].
// ---------------------------------------------------------------------------

#define SCAN_CHUNK 1024

typedef __attribute__((ext_vector_type(8))) short bf16x8;
typedef __attribute__((ext_vector_type(8))) unsigned short u16x8;
typedef __attribute__((ext_vector_type(4))) float f32x4;

__device__ __forceinline__ ushort f2b(float x) {
    union { float f; unsigned u; } v; v.f = x;
    unsigned r = (v.u + 0x7FFF + ((v.u >> 16) & 1)) >> 16;   // RNE
    return (ushort)r;
}
__device__ __forceinline__ float b2f(ushort u) {
    union { unsigned u; float f; } v; v.u = (unsigned)u << 16;
    return v.f;
}

// ---- pack Bp [K=512 x 128] (Wl_i; Wl_t; W_user@(Wr_i+Wr_t)) + fused bias ----
__global__ __launch_bounds__(256) void k_pack(
        const float* __restrict__ Wl_i, const float* __restrict__ Wl_t,
        const float* __restrict__ W_user, const float* __restrict__ b_user,
        const float* __restrict__ Wr_i, const float* __restrict__ Wr_t,
        const float* __restrict__ bl_i, const float* __restrict__ bl_t,
        ushort* __restrict__ Bp, float* __restrict__ bias) {
    int i = blockIdx.x * 256 + threadIdx.x;      // 65536 threads
    int j = i & 7, lane = (i >> 3) & 63, cf = (i >> 9) & 7, ks = i >> 12;
    int kk = ks * 32 + (lane >> 4) * 8 + j;
    int col = cf * 16 + (lane & 15);
    float v;
    if (kk < 128)      v = Wl_i[kk * 128 + col];
    else if (kk < 256) v = Wl_t[(kk - 128) * 128 + col];
    else {
        int k2 = kk - 256;                       // Wcomb[k2][col] inline
        float s = 0.f;
        for (int c1 = 0; c1 < 128; ++c1)
            s += W_user[k2 * 128 + c1] * (Wr_i[c1 * 128 + col] + Wr_t[c1 * 128 + col]);
        v = s;
    }
    Bp[i] = f2b(v);
    if (i < 128) {
        float b = bl_i[i] + bl_t[i];
        for (int k2 = 0; k2 < 128; ++k2)
            b += b_user[k2] * (Wr_i[k2 * 128 + i] + Wr_t[k2 * 128 + i]);
        bias[i] = b;
    }
}

// ---- fused front: [XCD-local hist+rank | bf16 convert] by block range ----
__global__ __launch_bounds__(256) void k_front(
        const float* __restrict__ x_image, const float* __restrict__ x_text,
        const int* __restrict__ edge_i, const int* __restrict__ edge_t,
        ushort* __restrict__ xib, ushort* __restrict__ xtb,
        int* __restrict__ degx, int* __restrict__ rank,
        int N, int M, int E, int nbH) {
    const int bid = blockIdx.x;
    const int tid = threadIdx.x;

    if (bid < 2 * nbH) {
        // ---- histogram + rank capture, per-XCD copy, L2-local atomics ----
        unsigned xcc;
        asm volatile("s_getreg_b32 %0, hwreg(HW_REG_XCC_ID)" : "=s"(xcc));
        xcc &= 7;
        int rel = (bid >= nbH) ? 1 : 0;
        int b = bid - rel * nbH;
        const int* eg = rel ? edge_t : edge_i;
        int* rk = rank + (size_t)rel * E;
        int* dg = degx + (size_t)xcc * M + rel * N;
        const int tag = (int)(xcc << 28);
        int e = b * 1024 + tid * 4;
        if (e + 3 < E) {
            int4 d4 = *reinterpret_cast<const int4*>(eg + E + e);
            int4 r4;
            r4.x = __hip_atomic_fetch_add(&dg[d4.x], 1, __ATOMIC_RELAXED,
                                          __HIP_MEMORY_SCOPE_WORKGROUP) | tag;
            r4.y = __hip_atomic_fetch_add(&dg[d4.y], 1, __ATOMIC_RELAXED,
                                          __HIP_MEMORY_SCOPE_WORKGROUP) | tag;
            r4.z = __hip_atomic_fetch_add(&dg[d4.z], 1, __ATOMIC_RELAXED,
                                          __HIP_MEMORY_SCOPE_WORKGROUP) | tag;
            r4.w = __hip_atomic_fetch_add(&dg[d4.w], 1, __ATOMIC_RELAXED,
                                          __HIP_MEMORY_SCOPE_WORKGROUP) | tag;
            *reinterpret_cast<int4*>(rk + e) = r4;
        } else {
            for (int j = 0; j < 4; ++j) {
                int ee = e + j;
                if (ee < E)
                    rk[ee] = __hip_atomic_fetch_add(&dg[eg[E + ee]], 1, __ATOMIC_RELAXED,
                                                    __HIP_MEMORY_SCOPE_WORKGROUP) | tag;
            }
        }
    } else {
        // ---- x_image/x_text f32 -> bf16 ----
        int t = (bid - 2 * nbH) * 256 + tid;
        int n8 = N * 16;
        if (t >= 2 * n8) return;
        int relc = (t >= n8) ? 1 : 0;
        const float* src = relc ? x_text : x_image;
        ushort* dst = relc ? xtb : xib;
        int i = relc ? t - n8 : t;
        float4 f0 = *reinterpret_cast<const float4*>(src + (size_t)i * 8);
        float4 f1 = *reinterpret_cast<const float4*>(src + (size_t)i * 8 + 4);
        u16x8 o;
        o[0] = f2b(f0.x); o[1] = f2b(f0.y); o[2] = f2b(f0.z); o[3] = f2b(f0.w);
        o[4] = f2b(f1.x); o[5] = f2b(f1.y); o[6] = f2b(f1.z); o[7] = f2b(f1.w);
        *reinterpret_cast<u16x8*>(dst + (size_t)i * 8) = o;
    }
}

// ---- merge 8 copies: degx -> per-copy excl. offsets; dtot; chunk sums ----
__global__ __launch_bounds__(256) void k_merge(
        int* __restrict__ degx, int* __restrict__ dtot,
        int* __restrict__ bsum, int M) {
    __shared__ int sh[256];
    const int t = threadIdx.x;
    const int base = blockIdx.x * SCAN_CHUNK;
    int loc = 0;
    #pragma unroll
    for (int j = 0; j < 4; ++j) {
        int d = base + j * 256 + t;
        if (d < M) {
            int s = 0;
            #pragma unroll
            for (int x = 0; x < 8; ++x) {
                size_t idx = (size_t)x * M + d;
                int c = degx[idx];
                degx[idx] = s;               // becomes per-copy exclusive offset
                s += c;
            }
            dtot[d] = s;
            loc += s;
        }
    }
    sh[t] = loc; __syncthreads();
    for (int off = 128; off > 0; off >>= 1) {
        if (t < off) sh[t] += sh[t + off];
        __syncthreads();
    }
    if (t == 0) bsum[blockIdx.x] = sh[0];
}

// ---- scan pass 2: parallel exclusive scan of chunk sums (nb <= 256) ----
__global__ __launch_bounds__(256) void k_scan2(int* __restrict__ bsum, int nb,
                                               int* __restrict__ rowptr, int M, int Etot) {
    __shared__ int sh[256];
    int t = threadIdx.x;
    int v = (t < nb) ? bsum[t] : 0;
    sh[t] = v; __syncthreads();
    for (int off = 1; off < 256; off <<= 1) {
        int add = (t >= off) ? sh[t - off] : 0;
        __syncthreads();
        sh[t] += add;
        __syncthreads();
    }
    if (t < nb) bsum[t] = sh[t] - v;       // exclusive
    if (t == 0) rowptr[M] = Etot;
}

// ---- scan pass 3: intra-chunk exclusive scan -> rowptr ----
__global__ __launch_bounds__(256) void k_scan3(const int* __restrict__ dtot,
                                               int* __restrict__ rowptr,
                                               const int* __restrict__ bsum, int M) {
    __shared__ int sh[256];
    int base = blockIdx.x * SCAN_CHUNK;
    int t = threadIdx.x;
    int v[4]; int s = 0;
    #pragma unroll
    for (int j = 0; j < 4; ++j) {
        int idx = base + 4 * t + j;
        v[j] = (idx < M) ? dtot[idx] : 0;
        s += v[j];
    }
    sh[t] = s; __syncthreads();
    for (int off = 1; off < 256; off <<= 1) {
        int add = (t >= off) ? sh[t - off] : 0;
        __syncthreads();
        sh[t] += add;
        __syncthreads();
    }
    int run = sh[t] - s + bsum[blockIdx.x];
    #pragma unroll
    for (int j = 0; j < 4; ++j) {
        int idx = base + 4 * t + j;
        if (idx < M) { rowptr[idx] = run; run += v[j]; }
    }
}

// ---- atomic-free scatter: col[rowptr[d] + off[xcc][d] + rank] = src ----
__global__ __launch_bounds__(256) void k_scatter2(
        const int* __restrict__ edge_i, const int* __restrict__ edge_t,
        const int* __restrict__ rank, const int* __restrict__ rowptr,
        const int* __restrict__ off, int* __restrict__ col,
        int N, int M, int E, int nbS) {
    const int bid = blockIdx.x;
    int rel = (bid >= nbS) ? 1 : 0;
    int b = bid - rel * nbS;
    const int* eg = rel ? edge_t : edge_i;
    const int* rk = rank + (size_t)rel * E;
    const int relN = rel * N;
    int e = b * 1024 + threadIdx.x * 4;
    if (e + 3 < E) {
        int4 d4 = *reinterpret_cast<const int4*>(eg + E + e);
        int4 s4 = *reinterpret_cast<const int4*>(eg + e);
        int4 r4 = *reinterpret_cast<const int4*>(rk + e);
        {
            int rb = relN + d4.x; unsigned r = (unsigned)r4.x;
            int p = rowptr[rb] + off[(size_t)(r >> 28) * M + rb] + (int)(r & 0x0FFFFFFFu);
            __builtin_nontemporal_store(s4.x, &col[p]);
        }
        {
            int rb = relN + d4.y; unsigned r = (unsigned)r4.y;
            int p = rowptr[rb] + off[(size_t)(r >> 28) * M + rb] + (int)(r & 0x0FFFFFFFu);
            __builtin_nontemporal_store(s4.y, &col[p]);
        }
        {
            int rb = relN + d4.z; unsigned r = (unsigned)r4.z;
            int p = rowptr[rb] + off[(size_t)(r >> 28) * M + rb] + (int)(r & 0x0FFFFFFFu);
            __builtin_nontemporal_store(s4.z, &col[p]);
        }
        {
            int rb = relN + d4.w; unsigned r = (unsigned)r4.w;
            int p = rowptr[rb] + off[(size_t)(r >> 28) * M + rb] + (int)(r & 0x0FFFFFFFu);
            __builtin_nontemporal_store(s4.w, &col[p]);
        }
    } else {
        for (int j = 0; j < 4; ++j) {
            int ee = e + j;
            if (ee < E) {
                int rb = relN + eg[E + ee];
                unsigned r = (unsigned)rk[ee];
                int p = rowptr[rb] + off[(size_t)(r >> 28) * M + rb] + (int)(r & 0x0FFFFFFFu);
                col[p] = eg[ee];
            }
        }
    }
}

// ---- gather-mean: 16 lanes/node, unroll-4, bf16 in/out, both relations ----
__global__ __launch_bounds__(256) void k_gather_mean(
        const ushort* __restrict__ xib, const ushort* __restrict__ xtb,
        const int* __restrict__ rowptr, const int* __restrict__ col,
        ushort* __restrict__ mi, ushort* __restrict__ mt, int N) {
    int t = blockIdx.x * 256 + threadIdx.x;
    int node = t >> 4, lane = t & 15;
    if (node >= N) return;
    int rel = blockIdx.y;
    const ushort* xs = rel ? xtb : xib;
    ushort* mean = rel ? mt : mi;
    int rb = rel * N + node;
    int beg = rowptr[rb], end = rowptr[rb + 1];
    float a0 = 0.f, a1 = 0.f, a2 = 0.f, a3 = 0.f,
          a4 = 0.f, a5 = 0.f, a6 = 0.f, a7 = 0.f;
    int j = beg;
    for (; j + 3 < end; j += 4) {
        int s0 = col[j], s1 = col[j + 1], s2 = col[j + 2], s3 = col[j + 3];
        u16x8 v0 = *reinterpret_cast<const u16x8*>(xs + (size_t)s0 * 128 + lane * 8);
        u16x8 v1 = *reinterpret_cast<const u16x8*>(xs + (size_t)s1 * 128 + lane * 8);
        u16x8 v2 = *reinterpret_cast<const u16x8*>(xs + (size_t)s2 * 128 + lane * 8);
        u16x8 v3 = *reinterpret_cast<const u16x8*>(xs + (size_t)s3 * 128 + lane * 8);
        a0 += (b2f(v0[0]) + b2f(v1[0])) + (b2f(v2[0]) + b2f(v3[0]));
        a1 += (b2f(v0[1]) + b2f(v1[1])) + (b2f(v2[1]) + b2f(v3[1]));
        a2 += (b2f(v0[2]) + b2f(v1[2])) + (b2f(v2[2]) + b2f(v3[2]));
        a3 += (b2f(v0[3]) + b2f(v1[3])) + (b2f(v2[3]) + b2f(v3[3]));
        a4 += (b2f(v0[4]) + b2f(v1[4])) + (b2f(v2[4]) + b2f(v3[4]));
        a5 += (b2f(v0[5]) + b2f(v1[5])) + (b2f(v2[5]) + b2f(v3[5]));
        a6 += (b2f(v0[6]) + b2f(v1[6])) + (b2f(v2[6]) + b2f(v3[6]));
        a7 += (b2f(v0[7]) + b2f(v1[7])) + (b2f(v2[7]) + b2f(v3[7]));
    }
    for (; j < end; ++j) {
        int s0 = col[j];
        u16x8 v0 = *reinterpret_cast<const u16x8*>(xs + (size_t)s0 * 128 + lane * 8);
        a0 += b2f(v0[0]); a1 += b2f(v0[1]); a2 += b2f(v0[2]); a3 += b2f(v0[3]);
        a4 += b2f(v0[4]); a5 += b2f(v0[5]); a6 += b2f(v0[6]); a7 += b2f(v0[7]);
    }
    float r = (end > beg) ? 1.0f / (float)(end - beg) : 0.0f;
    u16x8 o;
    o[0] = f2b(a0 * r); o[1] = f2b(a1 * r); o[2] = f2b(a2 * r); o[3] = f2b(a3 * r);
    o[4] = f2b(a4 * r); o[5] = f2b(a5 * r); o[6] = f2b(a6 * r); o[7] = f2b(a7 * r);
    *reinterpret_cast<u16x8*>(mean + (size_t)node * 128 + lane * 8) = o;
}

// ---- out = relu( [mi|mt|x_user](K=512) @ Bp + bias ) : MFMA ----
__global__ __launch_bounds__(256) void k_final_mfma(
        const ushort* __restrict__ mi, const ushort* __restrict__ mt,
        const float* __restrict__ x_user, const ushort* __restrict__ Bp,
        const float* __restrict__ bias, float* __restrict__ out, int N) {
    const int tid = threadIdx.x;
    const int wid = tid >> 6, lane = tid & 63;
    const int row16 = wid * 16 + (lane & 15);
    const int rA = min(blockIdx.x * 64 + row16, N - 1);
    const int kh = (lane >> 4) * 8;
    f32x4 acc[8] = {};

    #pragma unroll
    for (int ks = 0; ks < 8; ++ks) {             // means (bf16)
        const ushort* s = (ks < 4) ? mi : mt;
        bf16x8 a = *reinterpret_cast<const bf16x8*>(s + (size_t)rA * 128 + (ks & 3) * 32 + kh);
        #pragma unroll
        for (int cf = 0; cf < 8; ++cf) {
            bf16x8 bb = *reinterpret_cast<const bf16x8*>(Bp + ((ks * 8 + cf) * 64 + lane) * 8);
            acc[cf] = __builtin_amdgcn_mfma_f32_16x16x32_bf16(a, bb, acc[cf], 0, 0, 0);
        }
    }
    const float* Xr = x_user + (size_t)rA * 256;
    #pragma unroll
    for (int ks = 8; ks < 16; ++ks) {            // x_user (f32, inline cvt)
        int k0 = (ks - 8) * 32 + kh;
        float4 f0 = *reinterpret_cast<const float4*>(Xr + k0);
        float4 f1 = *reinterpret_cast<const float4*>(Xr + k0 + 4);
        bf16x8 aa;
        aa[0] = (short)f2b(f0.x); aa[1] = (short)f2b(f0.y);
        aa[2] = (short)f2b(f0.z); aa[3] = (short)f2b(f0.w);
        aa[4] = (short)f2b(f1.x); aa[5] = (short)f2b(f1.y);
        aa[6] = (short)f2b(f1.z); aa[7] = (short)f2b(f1.w);
        #pragma unroll
        for (int cf = 0; cf < 8; ++cf) {
            bf16x8 bb = *reinterpret_cast<const bf16x8*>(Bp + ((ks * 8 + cf) * 64 + lane) * 8);
            acc[cf] = __builtin_amdgcn_mfma_f32_16x16x32_bf16(aa, bb, acc[cf], 0, 0, 0);
        }
    }

    const int col0 = lane & 15;
    const int rbase = blockIdx.x * 64 + wid * 16 + (lane >> 4) * 4;
    #pragma unroll
    for (int cf = 0; cf < 8; ++cf) {
        int c = cf * 16 + col0;
        float bv = bias[c];
        #pragma unroll
        for (int r = 0; r < 4; ++r) {
            int row = rbase + r;
            if (row < N) out[(size_t)row * 128 + c] = fmaxf(acc[cf][r] + bv, 0.f);
        }
    }
}

extern "C" void kernel_launch(void* const* d_in, const int* in_sizes, int n_in,
                              void* d_out, int out_size, void* d_ws, size_t ws_size,
                              hipStream_t stream) {
    const float* x_user  = (const float*)d_in[0];
    const float* x_image = (const float*)d_in[1];
    const float* x_text  = (const float*)d_in[2];
    const int*   edge_i  = (const int*)d_in[3];
    const int*   edge_t  = (const int*)d_in[4];
    const float* W_user  = (const float*)d_in[5];
    const float* b_user  = (const float*)d_in[6];
    const float* Wl_img  = (const float*)d_in[7];
    const float* bl_img  = (const float*)d_in[8];
    const float* Wr_img  = (const float*)d_in[9];
    const float* Wl_txt  = (const float*)d_in[10];
    const float* bl_txt  = (const float*)d_in[11];
    const float* Wr_txt  = (const float*)d_in[12];

    const int N = in_sizes[0] / 256;   // 100000 nodes per type
    const int E = in_sizes[3] / 2;     // 800000 edges per relation
    const int M = 2 * N;
    const int NB = (M + SCAN_CHUNK - 1) / SCAN_CHUNK;   // <= 256

    ushort* xib    = (ushort*)d_ws;                // N*128
    ushort* xtb    = xib + (size_t)N * 128;        // N*128
    ushort* mi     = xtb + (size_t)N * 128;        // N*128
    ushort* mt     = mi  + (size_t)N * 128;        // N*128
    ushort* Bp     = mt  + (size_t)N * 128;        // 65536
    float*  bias   = (float*)(Bp + 65536);         // 128
    int*    degx   = (int*)(bias + 128);           // 8*M (counts -> offsets)
    int*    dtot   = degx + (size_t)8 * M;         // M
    int*    rowptr = dtot + M;                     // M+4
    int*    bscan  = rowptr + (M + 4);             // 256
    int*    rank   = bscan + 256;                  // 2E
    int*    col    = rank + (size_t)2 * E;         // 2E

    k_pack<<<256, 256, 0, stream>>>(Wl_img, Wl_txt, W_user, b_user,
                                    Wr_img, Wr_txt, bl_img, bl_txt, Bp, bias);

    hipMemsetAsync(degx, 0, (size_t)8 * M * sizeof(int), stream);

    const int nbH = (E + 1023) / 1024;             // hist blocks per relation
    const int nbC = (2 * N * 16 + 255) / 256;      // convert blocks
    k_front<<<2 * nbH + nbC, 256, 0, stream>>>(
        x_image, x_text, edge_i, edge_t, xib, xtb, degx, rank, N, M, E, nbH);

    k_merge<<<NB, 256, 0, stream>>>(degx, dtot, bscan, M);
    k_scan2<<<1, 256, 0, stream>>>(bscan, NB, rowptr, M, 2 * E);
    k_scan3<<<NB, 256, 0, stream>>>(dtot, rowptr, bscan, M);

    const int nbS = (E + 1023) / 1024;
    k_scatter2<<<2 * nbS, 256, 0, stream>>>(
        edge_i, edge_t, rank, rowptr, degx, col, N, M, E, nbS);

    {
        dim3 g((N * 16 + 255) / 256, 2);
        k_gather_mean<<<g, 256, 0, stream>>>(xib, xtb, rowptr, col, mi, mt, N);
    }

    k_final_mfma<<<(N + 63) / 64, 256, 0, stream>>>(
        mi, mt, x_user, Bp, bias, (float*)d_out, N);
}

// Round 9
// 217.613 us; speedup vs baseline: 1.3728x; 1.3728x over previous
//
#include <hip/hip_runtime.h>

// ---------------------------------------------------------------------------
// HeteroGNN, round 9: CSR via two-level bucket partition — ZERO global atomics.
//   out = relu( [mean_i | mean_t | x_user] @ [Wl_i; Wl_t; W_user@(Wr_i+Wr_t)]
//               + (b_user@(Wr_i+Wr_t) + bl_i + bl_t) )        [MFMA, K=512]
// Partition: key=(rel*N+dst), bucket=key>>10 (196 buckets).
//   k_front: per-chunk LDS bucket hist (+ bf16 convert, fused)
//   k_s1/k_s2: scan counts over blocks / bucket bases
//   k_part1: LDS-cursor scatter of (key,src) pairs into bucket regions
//   k_part2: per-bucket LDS hist/scan -> rowptr + col (dense L2-hot slice)
// MFMA 16x16x32_bf16: A row=lane&15, k=(lane>>4)*8+j; B col=lane&15;
// D col=lane&15, row=(lane>>4)*4+reg  [m89-verified].
// ---------------------------------------------------------------------------

#define BK 4096          // edges per level-1 block
#define MAXBUK 256       // >= nbuk = ceil(2N/1024) = 196

typedef __attribute__((ext_vector_type(8))) short bf16x8;
typedef __attribute__((ext_vector_type(8))) unsigned short u16x8;
typedef __attribute__((ext_vector_type(4))) float f32x4;

__device__ __forceinline__ ushort f2b(float x) {
    union { float f; unsigned u; } v; v.f = x;
    unsigned r = (v.u + 0x7FFF + ((v.u >> 16) & 1)) >> 16;   // RNE
    return (ushort)r;
}
__device__ __forceinline__ float b2f(ushort u) {
    union { unsigned u; float f; } v; v.u = (unsigned)u << 16;
    return v.f;
}

// ---- pack Bp [K=512 x 128] (Wl_i; Wl_t; W_user@(Wr_i+Wr_t)) + fused bias ----
__global__ __launch_bounds__(256) void k_pack(
        const float* __restrict__ Wl_i, const float* __restrict__ Wl_t,
        const float* __restrict__ W_user, const float* __restrict__ b_user,
        const float* __restrict__ Wr_i, const float* __restrict__ Wr_t,
        const float* __restrict__ bl_i, const float* __restrict__ bl_t,
        ushort* __restrict__ Bp, float* __restrict__ bias) {
    int i = blockIdx.x * 256 + threadIdx.x;      // 65536 threads
    int j = i & 7, lane = (i >> 3) & 63, cf = (i >> 9) & 7, ks = i >> 12;
    int kk = ks * 32 + (lane >> 4) * 8 + j;
    int col = cf * 16 + (lane & 15);
    float v;
    if (kk < 128)      v = Wl_i[kk * 128 + col];
    else if (kk < 256) v = Wl_t[(kk - 128) * 128 + col];
    else {
        int k2 = kk - 256;                       // Wcomb[k2][col] inline
        float s = 0.f;
        for (int c1 = 0; c1 < 128; ++c1)
            s += W_user[k2 * 128 + c1] * (Wr_i[c1 * 128 + col] + Wr_t[c1 * 128 + col]);
        v = s;
    }
    Bp[i] = f2b(v);
    if (i < 128) {
        float b = bl_i[i] + bl_t[i];
        for (int k2 = 0; k2 < 128; ++k2)
            b += b_user[k2] * (Wr_i[k2 * 128 + i] + Wr_t[k2 * 128 + i]);
        bias[i] = b;
    }
}

// ---- fused front: [bucket hist (LDS) | bf16 convert] by block range ----
__global__ __launch_bounds__(256) void k_front(
        const float* __restrict__ x_image, const float* __restrict__ x_text,
        const int* __restrict__ edge_i, const int* __restrict__ edge_t,
        ushort* __restrict__ xib, ushort* __restrict__ xtb,
        int* __restrict__ counts,
        int N, int E, int nblkR, int nbuk) {
    __shared__ int h[MAXBUK];
    const int bid = blockIdx.x;
    const int tid = threadIdx.x;
    const int NBLK = 2 * nblkR;

    if (bid < NBLK) {
        // ---- level-1 histogram of bucket = key>>10, LDS atomics only ----
        int rel = (bid >= nblkR) ? 1 : 0;
        int blk = bid - rel * nblkR;
        const int* eg = rel ? edge_t : edge_i;
        const int relN = rel * N;
        for (int i = tid; i < nbuk; i += 256) h[i] = 0;
        __syncthreads();
        int base = blk * BK;
        #pragma unroll
        for (int j = 0; j < 4; ++j) {
            int e = base + (j * 256 + tid) * 4;
            if (e + 3 < E) {
                int4 d4 = *reinterpret_cast<const int4*>(eg + E + e);
                atomicAdd(&h[(relN + d4.x) >> 10], 1);
                atomicAdd(&h[(relN + d4.y) >> 10], 1);
                atomicAdd(&h[(relN + d4.z) >> 10], 1);
                atomicAdd(&h[(relN + d4.w) >> 10], 1);
            } else {
                for (int q = 0; q < 4; ++q) {
                    int ee = e + q;
                    if (ee < E) atomicAdd(&h[(relN + eg[E + ee]) >> 10], 1);
                }
            }
        }
        __syncthreads();
        for (int i = tid; i < nbuk; i += 256) counts[(size_t)bid * nbuk + i] = h[i];
    } else {
        // ---- x_image/x_text f32 -> bf16 ----
        int t = (bid - NBLK) * 256 + tid;
        int n8 = N * 16;
        if (t >= 2 * n8) return;
        int relc = (t >= n8) ? 1 : 0;
        const float* src = relc ? x_text : x_image;
        ushort* dst = relc ? xtb : xib;
        int i = relc ? t - n8 : t;
        float4 f0 = *reinterpret_cast<const float4*>(src + (size_t)i * 8);
        float4 f1 = *reinterpret_cast<const float4*>(src + (size_t)i * 8 + 4);
        u16x8 o;
        o[0] = f2b(f0.x); o[1] = f2b(f0.y); o[2] = f2b(f0.z); o[3] = f2b(f0.w);
        o[4] = f2b(f1.x); o[5] = f2b(f1.y); o[6] = f2b(f1.z); o[7] = f2b(f1.w);
        *reinterpret_cast<u16x8*>(dst + (size_t)i * 8) = o;
    }
}

// ---- s1: per-bucket exclusive prefix over blocks (in-place) + totals ----
__global__ __launch_bounds__(256) void k_s1(int* __restrict__ counts,
                                            int* __restrict__ T,
                                            int NBLK, int nbuk) {
    __shared__ int a[512];
    __shared__ int ps[256];
    const int b = blockIdx.x, t = threadIdx.x;
    a[t]       = (t < NBLK)       ? counts[(size_t)t * nbuk + b] : 0;
    a[t + 256] = (t + 256 < NBLK) ? counts[(size_t)(t + 256) * nbuk + b] : 0;
    __syncthreads();
    int x0 = a[2 * t], x1 = a[2 * t + 1];
    int s = x0 + x1;
    ps[t] = s; __syncthreads();
    for (int off = 1; off < 256; off <<= 1) {
        int add = (t >= off) ? ps[t - off] : 0;
        __syncthreads();
        ps[t] += add;
        __syncthreads();
    }
    int ex = ps[t] - s;
    if (2 * t < NBLK)     counts[(size_t)(2 * t) * nbuk + b] = ex;
    if (2 * t + 1 < NBLK) counts[(size_t)(2 * t + 1) * nbuk + b] = ex + x0;
    if (t == 255) T[b] = ps[255];
}

// ---- s2: exclusive scan of bucket totals -> bucket bases ----
__global__ __launch_bounds__(256) void k_s2(const int* __restrict__ T,
                                            int* __restrict__ Bb,
                                            int* __restrict__ rowptr,
                                            int M, int Etot, int nbuk) {
    __shared__ int sh[256];
    int t = threadIdx.x;
    int v = (t < nbuk) ? T[t] : 0;
    sh[t] = v; __syncthreads();
    for (int off = 1; off < 256; off <<= 1) {
        int add = (t >= off) ? sh[t - off] : 0;
        __syncthreads();
        sh[t] += add;
        __syncthreads();
    }
    if (t < nbuk) Bb[t] = sh[t] - v;
    if (t == 0) { Bb[nbuk] = Etot; rowptr[M] = Etot; }
}

// ---- part1: scatter (key,src) pairs into bucket regions via LDS cursors ----
__global__ __launch_bounds__(256) void k_part1(
        const int* __restrict__ edge_i, const int* __restrict__ edge_t,
        const int* __restrict__ counts, const int* __restrict__ Bb,
        int2* __restrict__ pairs, int N, int E, int nblkR, int nbuk) {
    __shared__ int cur[MAXBUK];
    const int bid = blockIdx.x, tid = threadIdx.x;
    int rel = (bid >= nblkR) ? 1 : 0;
    int blk = bid - rel * nblkR;
    const int* eg = rel ? edge_t : edge_i;
    const int relN = rel * N;
    for (int i = tid; i < nbuk; i += 256)
        cur[i] = Bb[i] + counts[(size_t)bid * nbuk + i];
    __syncthreads();
    int base = blk * BK;
    #pragma unroll
    for (int j = 0; j < 4; ++j) {
        int e = base + (j * 256 + tid) * 4;
        if (e + 3 < E) {
            int4 d4 = *reinterpret_cast<const int4*>(eg + E + e);
            int4 s4 = *reinterpret_cast<const int4*>(eg + e);
            int k0 = relN + d4.x, k1 = relN + d4.y, k2 = relN + d4.z, k3 = relN + d4.w;
            int p0 = atomicAdd(&cur[k0 >> 10], 1); pairs[p0] = make_int2(k0, s4.x);
            int p1 = atomicAdd(&cur[k1 >> 10], 1); pairs[p1] = make_int2(k1, s4.y);
            int p2 = atomicAdd(&cur[k2 >> 10], 1); pairs[p2] = make_int2(k2, s4.z);
            int p3 = atomicAdd(&cur[k3 >> 10], 1); pairs[p3] = make_int2(k3, s4.w);
        } else {
            for (int q = 0; q < 4; ++q) {
                int ee = e + q;
                if (ee < E) {
                    int k0 = relN + eg[E + ee];
                    int p0 = atomicAdd(&cur[k0 >> 10], 1);
                    pairs[p0] = make_int2(k0, eg[ee]);
                }
            }
        }
    }
}

// ---- part2: per-bucket (1024 keys) hist/scan -> rowptr + col ----
__global__ __launch_bounds__(256) void k_part2(
        const int2* __restrict__ pairs, const int* __restrict__ Bb,
        int* __restrict__ rowptr, int* __restrict__ col, int M) {
    __shared__ int h[1024];
    __shared__ int ps[256];
    const int b = blockIdx.x, t = threadIdx.x;
    const int key0 = b << 10;
    const int beg = Bb[b], end = Bb[b + 1];
    for (int i = t; i < 1024; i += 256) h[i] = 0;
    __syncthreads();
    for (int p = beg + t; p < end; p += 256)
        atomicAdd(&h[pairs[p].x - key0], 1);
    __syncthreads();
    int v0 = h[4 * t], v1 = h[4 * t + 1], v2 = h[4 * t + 2], v3 = h[4 * t + 3];
    int s = v0 + v1 + v2 + v3;
    ps[t] = s; __syncthreads();
    for (int off = 1; off < 256; off <<= 1) {
        int add = (t >= off) ? ps[t - off] : 0;
        __syncthreads();
        ps[t] += add;
        __syncthreads();
    }
    int run = ps[t] - s + beg;
    __syncthreads();
    int k = key0 + 4 * t;
    if (k + 0 < M) rowptr[k + 0] = run; h[4 * t + 0] = run; run += v0;
    if (k + 1 < M) rowptr[k + 1] = run; h[4 * t + 1] = run; run += v1;
    if (k + 2 < M) rowptr[k + 2] = run; h[4 * t + 2] = run; run += v2;
    if (k + 3 < M) rowptr[k + 3] = run; h[4 * t + 3] = run;
    __syncthreads();
    for (int p = beg + t; p < end; p += 256) {
        int2 pr = pairs[p];
        int slot = atomicAdd(&h[pr.x - key0], 1);
        col[slot] = pr.y;
    }
}

// ---- gather-mean: 16 lanes/node, unroll-4, bf16 in/out, both relations ----
__global__ __launch_bounds__(256) void k_gather_mean(
        const ushort* __restrict__ xib, const ushort* __restrict__ xtb,
        const int* __restrict__ rowptr, const int* __restrict__ col,
        ushort* __restrict__ mi, ushort* __restrict__ mt, int N) {
    int t = blockIdx.x * 256 + threadIdx.x;
    int node = t >> 4, lane = t & 15;
    if (node >= N) return;
    int rel = blockIdx.y;
    const ushort* xs = rel ? xtb : xib;
    ushort* mean = rel ? mt : mi;
    int rb = rel * N + node;
    int beg = rowptr[rb], end = rowptr[rb + 1];
    float a0 = 0.f, a1 = 0.f, a2 = 0.f, a3 = 0.f,
          a4 = 0.f, a5 = 0.f, a6 = 0.f, a7 = 0.f;
    int j = beg;
    for (; j + 3 < end; j += 4) {
        int s0 = col[j], s1 = col[j + 1], s2 = col[j + 2], s3 = col[j + 3];
        u16x8 v0 = *reinterpret_cast<const u16x8*>(xs + (size_t)s0 * 128 + lane * 8);
        u16x8 v1 = *reinterpret_cast<const u16x8*>(xs + (size_t)s1 * 128 + lane * 8);
        u16x8 v2 = *reinterpret_cast<const u16x8*>(xs + (size_t)s2 * 128 + lane * 8);
        u16x8 v3 = *reinterpret_cast<const u16x8*>(xs + (size_t)s3 * 128 + lane * 8);
        a0 += (b2f(v0[0]) + b2f(v1[0])) + (b2f(v2[0]) + b2f(v3[0]));
        a1 += (b2f(v0[1]) + b2f(v1[1])) + (b2f(v2[1]) + b2f(v3[1]));
        a2 += (b2f(v0[2]) + b2f(v1[2])) + (b2f(v2[2]) + b2f(v3[2]));
        a3 += (b2f(v0[3]) + b2f(v1[3])) + (b2f(v2[3]) + b2f(v3[3]));
        a4 += (b2f(v0[4]) + b2f(v1[4])) + (b2f(v2[4]) + b2f(v3[4]));
        a5 += (b2f(v0[5]) + b2f(v1[5])) + (b2f(v2[5]) + b2f(v3[5]));
        a6 += (b2f(v0[6]) + b2f(v1[6])) + (b2f(v2[6]) + b2f(v3[6]));
        a7 += (b2f(v0[7]) + b2f(v1[7])) + (b2f(v2[7]) + b2f(v3[7]));
    }
    for (; j < end; ++j) {
        int s0 = col[j];
        u16x8 v0 = *reinterpret_cast<const u16x8*>(xs + (size_t)s0 * 128 + lane * 8);
        a0 += b2f(v0[0]); a1 += b2f(v0[1]); a2 += b2f(v0[2]); a3 += b2f(v0[3]);
        a4 += b2f(v0[4]); a5 += b2f(v0[5]); a6 += b2f(v0[6]); a7 += b2f(v0[7]);
    }
    float r = (end > beg) ? 1.0f / (float)(end - beg) : 0.0f;
    u16x8 o;
    o[0] = f2b(a0 * r); o[1] = f2b(a1 * r); o[2] = f2b(a2 * r); o[3] = f2b(a3 * r);
    o[4] = f2b(a4 * r); o[5] = f2b(a5 * r); o[6] = f2b(a6 * r); o[7] = f2b(a7 * r);
    *reinterpret_cast<u16x8*>(mean + (size_t)node * 128 + lane * 8) = o;
}

// ---- out = relu( [mi|mt|x_user](K=512) @ Bp + bias ) : MFMA ----
__global__ __launch_bounds__(256) void k_final_mfma(
        const ushort* __restrict__ mi, const ushort* __restrict__ mt,
        const float* __restrict__ x_user, const ushort* __restrict__ Bp,
        const float* __restrict__ bias, float* __restrict__ out, int N) {
    const int tid = threadIdx.x;
    const int wid = tid >> 6, lane = tid & 63;
    const int row16 = wid * 16 + (lane & 15);
    const int rA = min(blockIdx.x * 64 + row16, N - 1);
    const int kh = (lane >> 4) * 8;
    f32x4 acc[8] = {};

    #pragma unroll
    for (int ks = 0; ks < 8; ++ks) {             // means (bf16)
        const ushort* s = (ks < 4) ? mi : mt;
        bf16x8 a = *reinterpret_cast<const bf16x8*>(s + (size_t)rA * 128 + (ks & 3) * 32 + kh);
        #pragma unroll
        for (int cf = 0; cf < 8; ++cf) {
            bf16x8 bb = *reinterpret_cast<const bf16x8*>(Bp + ((ks * 8 + cf) * 64 + lane) * 8);
            acc[cf] = __builtin_amdgcn_mfma_f32_16x16x32_bf16(a, bb, acc[cf], 0, 0, 0);
        }
    }
    const float* Xr = x_user + (size_t)rA * 256;
    #pragma unroll
    for (int ks = 8; ks < 16; ++ks) {            // x_user (f32, inline cvt)
        int k0 = (ks - 8) * 32 + kh;
        float4 f0 = *reinterpret_cast<const float4*>(Xr + k0);
        float4 f1 = *reinterpret_cast<const float4*>(Xr + k0 + 4);
        bf16x8 aa;
        aa[0] = (short)f2b(f0.x); aa[1] = (short)f2b(f0.y);
        aa[2] = (short)f2b(f0.z); aa[3] = (short)f2b(f0.w);
        aa[4] = (short)f2b(f1.x); aa[5] = (short)f2b(f1.y);
        aa[6] = (short)f2b(f1.z); aa[7] = (short)f2b(f1.w);
        #pragma unroll
        for (int cf = 0; cf < 8; ++cf) {
            bf16x8 bb = *reinterpret_cast<const bf16x8*>(Bp + ((ks * 8 + cf) * 64 + lane) * 8);
            acc[cf] = __builtin_amdgcn_mfma_f32_16x16x32_bf16(aa, bb, acc[cf], 0, 0, 0);
        }
    }

    const int col0 = lane & 15;
    const int rbase = blockIdx.x * 64 + wid * 16 + (lane >> 4) * 4;
    #pragma unroll
    for (int cf = 0; cf < 8; ++cf) {
        int c = cf * 16 + col0;
        float bv = bias[c];
        #pragma unroll
        for (int r = 0; r < 4; ++r) {
            int row = rbase + r;
            if (row < N) out[(size_t)row * 128 + c] = fmaxf(acc[cf][r] + bv, 0.f);
        }
    }
}

extern "C" void kernel_launch(void* const* d_in, const int* in_sizes, int n_in,
                              void* d_out, int out_size, void* d_ws, size_t ws_size,
                              hipStream_t stream) {
    const float* x_user  = (const float*)d_in[0];
    const float* x_image = (const float*)d_in[1];
    const float* x_text  = (const float*)d_in[2];
    const int*   edge_i  = (const int*)d_in[3];
    const int*   edge_t  = (const int*)d_in[4];
    const float* W_user  = (const float*)d_in[5];
    const float* b_user  = (const float*)d_in[6];
    const float* Wl_img  = (const float*)d_in[7];
    const float* bl_img  = (const float*)d_in[8];
    const float* Wr_img  = (const float*)d_in[9];
    const float* Wl_txt  = (const float*)d_in[10];
    const float* bl_txt  = (const float*)d_in[11];
    const float* Wr_txt  = (const float*)d_in[12];

    const int N = in_sizes[0] / 256;   // 100000 nodes per type
    const int E = in_sizes[3] / 2;     // 800000 edges per relation
    const int M = 2 * N;
    const int nblkR = (E + BK - 1) / BK;           // 196
    const int NBLK = 2 * nblkR;                    // 392 (<=512 for k_s1)
    const int nbuk = (M + 1023) >> 10;             // 196 (<=MAXBUK)

    ushort* xib    = (ushort*)d_ws;                // N*128
    ushort* xtb    = xib + (size_t)N * 128;        // N*128
    ushort* mi     = xtb + (size_t)N * 128;        // N*128
    ushort* mt     = mi  + (size_t)N * 128;        // N*128
    ushort* Bp     = mt  + (size_t)N * 128;        // 65536
    float*  bias   = (float*)(Bp + 65536);         // 128
    int*    counts = (int*)(bias + 128);           // NBLK*nbuk
    int*    T      = counts + (size_t)NBLK * nbuk; // 256
    int*    Bb     = T + 256;                      // nbuk+1 (pad 260)
    int*    rowptr = Bb + 260;                     // M+4
    int*    col    = rowptr + (M + 4);             // 2E
    int2*   pairs  = (int2*)(col + (size_t)2 * E); // 2E int2 (8B aligned: offset even)

    k_pack<<<256, 256, 0, stream>>>(Wl_img, Wl_txt, W_user, b_user,
                                    Wr_img, Wr_txt, bl_img, bl_txt, Bp, bias);

    const int nbC = (2 * N * 16 + 255) / 256;      // convert blocks
    k_front<<<NBLK + nbC, 256, 0, stream>>>(
        x_image, x_text, edge_i, edge_t, xib, xtb, counts, N, E, nblkR, nbuk);

    k_s1<<<nbuk, 256, 0, stream>>>(counts, T, NBLK, nbuk);
    k_s2<<<1, 256, 0, stream>>>(T, Bb, rowptr, M, 2 * E, nbuk);
    k_part1<<<NBLK, 256, 0, stream>>>(edge_i, edge_t, counts, Bb, pairs,
                                      N, E, nblkR, nbuk);
    k_part2<<<nbuk, 256, 0, stream>>>(pairs, Bb, rowptr, col, M);

    {
        dim3 g((N * 16 + 255) / 256, 2);
        k_gather_mean<<<g, 256, 0, stream>>>(xib, xtb, rowptr, col, mi, mt, N);
    }

    k_final_mfma<<<(N + 63) / 64, 256, 0, stream>>>(
        mi, mt, x_user, Bp, bias, (float*)d_out, N);
}

// Round 10
// 195.233 us; speedup vs baseline: 1.5302x; 1.1146x over previous
//
#include <hip/hip_runtime.h>

// ---------------------------------------------------------------------------
// HeteroGNN, round 10: LDS-staged B in the final MFMA (r9 profile: B-operand
// L2 re-streaming + load latency was 89us; MFMA work itself is ~5us).
//   out = relu( [mean_i | mean_t | x_user] @ [Wl_i; Wl_t; W_user@(Wr_i+Wr_t)]
//               + (b_user@(Wr_i+Wr_t) + bl_i + bl_t) )        [MFMA, K=512]
// CSR: two-level bucket partition, zero global atomics (r9).
// k_final_mfma: 512 thr / 8 waves / 256 rows per block; B staged in LDS in
// two 64KB halves; 32 rows/wave (2 A-frags) -> 16 MFMA per 8 ds_read_b128.
// MFMA 16x16x32_bf16: A row=lane&15, k=(lane>>4)*8+j; B col=lane&15;
// D col=lane&15, row=(lane>>4)*4+reg  [m89-verified].
// ---------------------------------------------------------------------------

#define BK 4096          // edges per level-1 block
#define MAXBUK 256       // >= nbuk = ceil(2N/1024) = 196

typedef __attribute__((ext_vector_type(8))) short bf16x8;
typedef __attribute__((ext_vector_type(8))) unsigned short u16x8;
typedef __attribute__((ext_vector_type(4))) float f32x4;

__device__ __forceinline__ ushort f2b(float x) {
    union { float f; unsigned u; } v; v.f = x;
    unsigned r = (v.u + 0x7FFF + ((v.u >> 16) & 1)) >> 16;   // RNE
    return (ushort)r;
}
__device__ __forceinline__ float b2f(ushort u) {
    union { unsigned u; float f; } v; v.u = (unsigned)u << 16;
    return v.f;
}

// ---- pack Bp [K=512 x 128] (Wl_i; Wl_t; W_user@(Wr_i+Wr_t)) + fused bias ----
__global__ __launch_bounds__(256) void k_pack(
        const float* __restrict__ Wl_i, const float* __restrict__ Wl_t,
        const float* __restrict__ W_user, const float* __restrict__ b_user,
        const float* __restrict__ Wr_i, const float* __restrict__ Wr_t,
        const float* __restrict__ bl_i, const float* __restrict__ bl_t,
        ushort* __restrict__ Bp, float* __restrict__ bias) {
    int i = blockIdx.x * 256 + threadIdx.x;      // 65536 threads
    int j = i & 7, lane = (i >> 3) & 63, cf = (i >> 9) & 7, ks = i >> 12;
    int kk = ks * 32 + (lane >> 4) * 8 + j;
    int col = cf * 16 + (lane & 15);
    float v;
    if (kk < 128)      v = Wl_i[kk * 128 + col];
    else if (kk < 256) v = Wl_t[(kk - 128) * 128 + col];
    else {
        int k2 = kk - 256;                       // Wcomb[k2][col] inline
        float s = 0.f;
        for (int c1 = 0; c1 < 128; ++c1)
            s += W_user[k2 * 128 + c1] * (Wr_i[c1 * 128 + col] + Wr_t[c1 * 128 + col]);
        v = s;
    }
    Bp[i] = f2b(v);
    if (i < 128) {
        float b = bl_i[i] + bl_t[i];
        for (int k2 = 0; k2 < 128; ++k2)
            b += b_user[k2] * (Wr_i[k2 * 128 + i] + Wr_t[k2 * 128 + i]);
        bias[i] = b;
    }
}

// ---- fused front: [bucket hist (LDS) | bf16 convert] by block range ----
__global__ __launch_bounds__(256) void k_front(
        const float* __restrict__ x_image, const float* __restrict__ x_text,
        const int* __restrict__ edge_i, const int* __restrict__ edge_t,
        ushort* __restrict__ xib, ushort* __restrict__ xtb,
        int* __restrict__ counts,
        int N, int E, int nblkR, int nbuk) {
    __shared__ int h[MAXBUK];
    const int bid = blockIdx.x;
    const int tid = threadIdx.x;
    const int NBLK = 2 * nblkR;

    if (bid < NBLK) {
        int rel = (bid >= nblkR) ? 1 : 0;
        int blk = bid - rel * nblkR;
        const int* eg = rel ? edge_t : edge_i;
        const int relN = rel * N;
        for (int i = tid; i < nbuk; i += 256) h[i] = 0;
        __syncthreads();
        int base = blk * BK;
        #pragma unroll
        for (int j = 0; j < 4; ++j) {
            int e = base + (j * 256 + tid) * 4;
            if (e + 3 < E) {
                int4 d4 = *reinterpret_cast<const int4*>(eg + E + e);
                atomicAdd(&h[(relN + d4.x) >> 10], 1);
                atomicAdd(&h[(relN + d4.y) >> 10], 1);
                atomicAdd(&h[(relN + d4.z) >> 10], 1);
                atomicAdd(&h[(relN + d4.w) >> 10], 1);
            } else {
                for (int q = 0; q < 4; ++q) {
                    int ee = e + q;
                    if (ee < E) atomicAdd(&h[(relN + eg[E + ee]) >> 10], 1);
                }
            }
        }
        __syncthreads();
        for (int i = tid; i < nbuk; i += 256) counts[(size_t)bid * nbuk + i] = h[i];
    } else {
        int t = (bid - NBLK) * 256 + tid;
        int n8 = N * 16;
        if (t >= 2 * n8) return;
        int relc = (t >= n8) ? 1 : 0;
        const float* src = relc ? x_text : x_image;
        ushort* dst = relc ? xtb : xib;
        int i = relc ? t - n8 : t;
        float4 f0 = *reinterpret_cast<const float4*>(src + (size_t)i * 8);
        float4 f1 = *reinterpret_cast<const float4*>(src + (size_t)i * 8 + 4);
        u16x8 o;
        o[0] = f2b(f0.x); o[1] = f2b(f0.y); o[2] = f2b(f0.z); o[3] = f2b(f0.w);
        o[4] = f2b(f1.x); o[5] = f2b(f1.y); o[6] = f2b(f1.z); o[7] = f2b(f1.w);
        *reinterpret_cast<u16x8*>(dst + (size_t)i * 8) = o;
    }
}

// ---- s1: per-bucket exclusive prefix over blocks (in-place) + totals ----
__global__ __launch_bounds__(256) void k_s1(int* __restrict__ counts,
                                            int* __restrict__ T,
                                            int NBLK, int nbuk) {
    __shared__ int a[512];
    __shared__ int ps[256];
    const int b = blockIdx.x, t = threadIdx.x;
    a[t]       = (t < NBLK)       ? counts[(size_t)t * nbuk + b] : 0;
    a[t + 256] = (t + 256 < NBLK) ? counts[(size_t)(t + 256) * nbuk + b] : 0;
    __syncthreads();
    int x0 = a[2 * t], x1 = a[2 * t + 1];
    int s = x0 + x1;
    ps[t] = s; __syncthreads();
    for (int off = 1; off < 256; off <<= 1) {
        int add = (t >= off) ? ps[t - off] : 0;
        __syncthreads();
        ps[t] += add;
        __syncthreads();
    }
    int ex = ps[t] - s;
    if (2 * t < NBLK)     counts[(size_t)(2 * t) * nbuk + b] = ex;
    if (2 * t + 1 < NBLK) counts[(size_t)(2 * t + 1) * nbuk + b] = ex + x0;
    if (t == 255) T[b] = ps[255];
}

// ---- s2: exclusive scan of bucket totals -> bucket bases ----
__global__ __launch_bounds__(256) void k_s2(const int* __restrict__ T,
                                            int* __restrict__ Bb,
                                            int* __restrict__ rowptr,
                                            int M, int Etot, int nbuk) {
    __shared__ int sh[256];
    int t = threadIdx.x;
    int v = (t < nbuk) ? T[t] : 0;
    sh[t] = v; __syncthreads();
    for (int off = 1; off < 256; off <<= 1) {
        int add = (t >= off) ? sh[t - off] : 0;
        __syncthreads();
        sh[t] += add;
        __syncthreads();
    }
    if (t < nbuk) Bb[t] = sh[t] - v;
    if (t == 0) { Bb[nbuk] = Etot; rowptr[M] = Etot; }
}

// ---- part1: scatter (key,src) pairs into bucket regions via LDS cursors ----
__global__ __launch_bounds__(256) void k_part1(
        const int* __restrict__ edge_i, const int* __restrict__ edge_t,
        const int* __restrict__ counts, const int* __restrict__ Bb,
        int2* __restrict__ pairs, int N, int E, int nblkR, int nbuk) {
    __shared__ int cur[MAXBUK];
    const int bid = blockIdx.x, tid = threadIdx.x;
    int rel = (bid >= nblkR) ? 1 : 0;
    int blk = bid - rel * nblkR;
    const int* eg = rel ? edge_t : edge_i;
    const int relN = rel * N;
    for (int i = tid; i < nbuk; i += 256)
        cur[i] = Bb[i] + counts[(size_t)bid * nbuk + i];
    __syncthreads();
    int base = blk * BK;
    #pragma unroll
    for (int j = 0; j < 4; ++j) {
        int e = base + (j * 256 + tid) * 4;
        if (e + 3 < E) {
            int4 d4 = *reinterpret_cast<const int4*>(eg + E + e);
            int4 s4 = *reinterpret_cast<const int4*>(eg + e);
            int k0 = relN + d4.x, k1 = relN + d4.y, k2 = relN + d4.z, k3 = relN + d4.w;
            int p0 = atomicAdd(&cur[k0 >> 10], 1); pairs[p0] = make_int2(k0, s4.x);
            int p1 = atomicAdd(&cur[k1 >> 10], 1); pairs[p1] = make_int2(k1, s4.y);
            int p2 = atomicAdd(&cur[k2 >> 10], 1); pairs[p2] = make_int2(k2, s4.z);
            int p3 = atomicAdd(&cur[k3 >> 10], 1); pairs[p3] = make_int2(k3, s4.w);
        } else {
            for (int q = 0; q < 4; ++q) {
                int ee = e + q;
                if (ee < E) {
                    int k0 = relN + eg[E + ee];
                    int p0 = atomicAdd(&cur[k0 >> 10], 1);
                    pairs[p0] = make_int2(k0, eg[ee]);
                }
            }
        }
    }
}

// ---- part2: per-bucket (1024 keys) hist/scan -> rowptr + col ----
__global__ __launch_bounds__(256) void k_part2(
        const int2* __restrict__ pairs, const int* __restrict__ Bb,
        int* __restrict__ rowptr, int* __restrict__ col, int M) {
    __shared__ int h[1024];
    __shared__ int ps[256];
    const int b = blockIdx.x, t = threadIdx.x;
    const int key0 = b << 10;
    const int beg = Bb[b], end = Bb[b + 1];
    for (int i = t; i < 1024; i += 256) h[i] = 0;
    __syncthreads();
    for (int p = beg + t; p < end; p += 256)
        atomicAdd(&h[pairs[p].x - key0], 1);
    __syncthreads();
    int v0 = h[4 * t], v1 = h[4 * t + 1], v2 = h[4 * t + 2], v3 = h[4 * t + 3];
    int s = v0 + v1 + v2 + v3;
    ps[t] = s; __syncthreads();
    for (int off = 1; off < 256; off <<= 1) {
        int add = (t >= off) ? ps[t - off] : 0;
        __syncthreads();
        ps[t] += add;
        __syncthreads();
    }
    int run = ps[t] - s + beg;
    __syncthreads();
    int k = key0 + 4 * t;
    if (k + 0 < M) rowptr[k + 0] = run; h[4 * t + 0] = run; run += v0;
    if (k + 1 < M) rowptr[k + 1] = run; h[4 * t + 1] = run; run += v1;
    if (k + 2 < M) rowptr[k + 2] = run; h[4 * t + 2] = run; run += v2;
    if (k + 3 < M) rowptr[k + 3] = run; h[4 * t + 3] = run;
    __syncthreads();
    for (int p = beg + t; p < end; p += 256) {
        int2 pr = pairs[p];
        int slot = atomicAdd(&h[pr.x - key0], 1);
        col[slot] = pr.y;
    }
}

// ---- gather-mean: 16 lanes/node, unroll-4, bf16 in/out, both relations ----
__global__ __launch_bounds__(256) void k_gather_mean(
        const ushort* __restrict__ xib, const ushort* __restrict__ xtb,
        const int* __restrict__ rowptr, const int* __restrict__ col,
        ushort* __restrict__ mi, ushort* __restrict__ mt, int N) {
    int t = blockIdx.x * 256 + threadIdx.x;
    int node = t >> 4, lane = t & 15;
    if (node >= N) return;
    int rel = blockIdx.y;
    const ushort* xs = rel ? xtb : xib;
    ushort* mean = rel ? mt : mi;
    int rb = rel * N + node;
    int beg = rowptr[rb], end = rowptr[rb + 1];
    float a0 = 0.f, a1 = 0.f, a2 = 0.f, a3 = 0.f,
          a4 = 0.f, a5 = 0.f, a6 = 0.f, a7 = 0.f;
    int j = beg;
    for (; j + 3 < end; j += 4) {
        int s0 = col[j], s1 = col[j + 1], s2 = col[j + 2], s3 = col[j + 3];
        u16x8 v0 = *reinterpret_cast<const u16x8*>(xs + (size_t)s0 * 128 + lane * 8);
        u16x8 v1 = *reinterpret_cast<const u16x8*>(xs + (size_t)s1 * 128 + lane * 8);
        u16x8 v2 = *reinterpret_cast<const u16x8*>(xs + (size_t)s2 * 128 + lane * 8);
        u16x8 v3 = *reinterpret_cast<const u16x8*>(xs + (size_t)s3 * 128 + lane * 8);
        a0 += (b2f(v0[0]) + b2f(v1[0])) + (b2f(v2[0]) + b2f(v3[0]));
        a1 += (b2f(v0[1]) + b2f(v1[1])) + (b2f(v2[1]) + b2f(v3[1]));
        a2 += (b2f(v0[2]) + b2f(v1[2])) + (b2f(v2[2]) + b2f(v3[2]));
        a3 += (b2f(v0[3]) + b2f(v1[3])) + (b2f(v2[3]) + b2f(v3[3]));
        a4 += (b2f(v0[4]) + b2f(v1[4])) + (b2f(v2[4]) + b2f(v3[4]));
        a5 += (b2f(v0[5]) + b2f(v1[5])) + (b2f(v2[5]) + b2f(v3[5]));
        a6 += (b2f(v0[6]) + b2f(v1[6])) + (b2f(v2[6]) + b2f(v3[6]));
        a7 += (b2f(v0[7]) + b2f(v1[7])) + (b2f(v2[7]) + b2f(v3[7]));
    }
    for (; j < end; ++j) {
        int s0 = col[j];
        u16x8 v0 = *reinterpret_cast<const u16x8*>(xs + (size_t)s0 * 128 + lane * 8);
        a0 += b2f(v0[0]); a1 += b2f(v0[1]); a2 += b2f(v0[2]); a3 += b2f(v0[3]);
        a4 += b2f(v0[4]); a5 += b2f(v0[5]); a6 += b2f(v0[6]); a7 += b2f(v0[7]);
    }
    float r = (end > beg) ? 1.0f / (float)(end - beg) : 0.0f;
    u16x8 o;
    o[0] = f2b(a0 * r); o[1] = f2b(a1 * r); o[2] = f2b(a2 * r); o[3] = f2b(a3 * r);
    o[4] = f2b(a4 * r); o[5] = f2b(a5 * r); o[6] = f2b(a6 * r); o[7] = f2b(a7 * r);
    *reinterpret_cast<u16x8*>(mean + (size_t)node * 128 + lane * 8) = o;
}

// ---- out = relu( [mi|mt|x_user](K=512) @ Bp + bias ) : MFMA, B in LDS ----
// 512 thr / 8 waves, 256 rows per block (32 rows/wave), B staged in 2x64KB.
__global__ __launch_bounds__(512) void k_final_mfma(
        const ushort* __restrict__ mi, const ushort* __restrict__ mt,
        const float* __restrict__ x_user, const ushort* __restrict__ Bp,
        const float* __restrict__ bias, float* __restrict__ out, int N) {
    __shared__ u16x8 bl8[4096];                  // 64 KB half of B
    const int tid = threadIdx.x;
    const int wid = tid >> 6, lane = tid & 63;
    const int r0g = blockIdx.x * 256 + wid * 32 + (lane & 15);
    const int rA0 = min(r0g, N - 1);
    const int rA1 = min(r0g + 16, N - 1);
    const int kh = (lane >> 4) * 8;
    f32x4 acc0[8] = {}, acc1[8] = {};

    const u16x8* Bp8 = reinterpret_cast<const u16x8*>(Bp);

    #pragma unroll
    for (int h = 0; h < 2; ++h) {
        // ---- stage 64KB half of B into LDS (linear copy) ----
        if (h) __syncthreads();                  // protect previous half's reads
        #pragma unroll
        for (int it = 0; it < 8; ++it)
            bl8[it * 512 + tid] = Bp8[h * 4096 + it * 512 + tid];
        __syncthreads();

        if (h == 0) {
            // ---- ks 0..7: A from mi/mt (bf16) ----
            #pragma unroll
            for (int ks = 0; ks < 8; ++ks) {
                const ushort* s = (ks < 4) ? mi : mt;
                bf16x8 a0 = *reinterpret_cast<const bf16x8*>(s + (size_t)rA0 * 128 + (ks & 3) * 32 + kh);
                bf16x8 a1 = *reinterpret_cast<const bf16x8*>(s + (size_t)rA1 * 128 + (ks & 3) * 32 + kh);
                #pragma unroll
                for (int cf = 0; cf < 8; ++cf) {
                    bf16x8 bb = *reinterpret_cast<const bf16x8*>(&bl8[(ks * 8 + cf) * 64 + lane]);
                    acc0[cf] = __builtin_amdgcn_mfma_f32_16x16x32_bf16(a0, bb, acc0[cf], 0, 0, 0);
                    acc1[cf] = __builtin_amdgcn_mfma_f32_16x16x32_bf16(a1, bb, acc1[cf], 0, 0, 0);
                }
            }
        } else {
            // ---- ks 8..15: A from x_user (f32, inline cvt) ----
            const float* Xr0 = x_user + (size_t)rA0 * 256;
            const float* Xr1 = x_user + (size_t)rA1 * 256;
            #pragma unroll
            for (int ks = 0; ks < 8; ++ks) {
                int k0 = ks * 32 + kh;
                float4 f0 = *reinterpret_cast<const float4*>(Xr0 + k0);
                float4 f1 = *reinterpret_cast<const float4*>(Xr0 + k0 + 4);
                float4 g0 = *reinterpret_cast<const float4*>(Xr1 + k0);
                float4 g1 = *reinterpret_cast<const float4*>(Xr1 + k0 + 4);
                bf16x8 a0, a1;
                a0[0] = (short)f2b(f0.x); a0[1] = (short)f2b(f0.y);
                a0[2] = (short)f2b(f0.z); a0[3] = (short)f2b(f0.w);
                a0[4] = (short)f2b(f1.x); a0[5] = (short)f2b(f1.y);
                a0[6] = (short)f2b(f1.z); a0[7] = (short)f2b(f1.w);
                a1[0] = (short)f2b(g0.x); a1[1] = (short)f2b(g0.y);
                a1[2] = (short)f2b(g0.z); a1[3] = (short)f2b(g0.w);
                a1[4] = (short)f2b(g1.x); a1[5] = (short)f2b(g1.y);
                a1[6] = (short)f2b(g1.z); a1[7] = (short)f2b(g1.w);
                #pragma unroll
                for (int cf = 0; cf < 8; ++cf) {
                    bf16x8 bb = *reinterpret_cast<const bf16x8*>(&bl8[(ks * 8 + cf) * 64 + lane]);
                    acc0[cf] = __builtin_amdgcn_mfma_f32_16x16x32_bf16(a0, bb, acc0[cf], 0, 0, 0);
                    acc1[cf] = __builtin_amdgcn_mfma_f32_16x16x32_bf16(a1, bb, acc1[cf], 0, 0, 0);
                }
            }
        }
    }

    // ---- epilogue: bias + relu + store (2 row groups) ----
    const int col0 = lane & 15;
    const int rbase = blockIdx.x * 256 + wid * 32 + (lane >> 4) * 4;
    #pragma unroll
    for (int cf = 0; cf < 8; ++cf) {
        int c = cf * 16 + col0;
        float bv = bias[c];
        #pragma unroll
        for (int r = 0; r < 4; ++r) {
            int row = rbase + r;
            if (row < N) out[(size_t)row * 128 + c] = fmaxf(acc0[cf][r] + bv, 0.f);
            int row2 = rbase + 16 + r;
            if (row2 < N) out[(size_t)row2 * 128 + c] = fmaxf(acc1[cf][r] + bv, 0.f);
        }
    }
}

extern "C" void kernel_launch(void* const* d_in, const int* in_sizes, int n_in,
                              void* d_out, int out_size, void* d_ws, size_t ws_size,
                              hipStream_t stream) {
    const float* x_user  = (const float*)d_in[0];
    const float* x_image = (const float*)d_in[1];
    const float* x_text  = (const float*)d_in[2];
    const int*   edge_i  = (const int*)d_in[3];
    const int*   edge_t  = (const int*)d_in[4];
    const float* W_user  = (const float*)d_in[5];
    const float* b_user  = (const float*)d_in[6];
    const float* Wl_img  = (const float*)d_in[7];
    const float* bl_img  = (const float*)d_in[8];
    const float* Wr_img  = (const float*)d_in[9];
    const float* Wl_txt  = (const float*)d_in[10];
    const float* bl_txt  = (const float*)d_in[11];
    const float* Wr_txt  = (const float*)d_in[12];

    const int N = in_sizes[0] / 256;   // 100000 nodes per type
    const int E = in_sizes[3] / 2;     // 800000 edges per relation
    const int M = 2 * N;
    const int nblkR = (E + BK - 1) / BK;           // 196
    const int NBLK = 2 * nblkR;                    // 392 (<=512 for k_s1)
    const int nbuk = (M + 1023) >> 10;             // 196 (<=MAXBUK)

    ushort* xib    = (ushort*)d_ws;                // N*128
    ushort* xtb    = xib + (size_t)N * 128;        // N*128
    ushort* mi     = xtb + (size_t)N * 128;        // N*128
    ushort* mt     = mi  + (size_t)N * 128;        // N*128
    ushort* Bp     = mt  + (size_t)N * 128;        // 65536
    float*  bias   = (float*)(Bp + 65536);         // 128
    int*    counts = (int*)(bias + 128);           // NBLK*nbuk
    int*    T      = counts + (size_t)NBLK * nbuk; // 256
    int*    Bb     = T + 256;                      // nbuk+1 (pad 260)
    int*    rowptr = Bb + 260;                     // M+4
    int*    col    = rowptr + (M + 4);             // 2E
    int2*   pairs  = (int2*)(col + (size_t)2 * E); // 2E int2

    k_pack<<<256, 256, 0, stream>>>(Wl_img, Wl_txt, W_user, b_user,
                                    Wr_img, Wr_txt, bl_img, bl_txt, Bp, bias);

    const int nbC = (2 * N * 16 + 255) / 256;      // convert blocks
    k_front<<<NBLK + nbC, 256, 0, stream>>>(
        x_image, x_text, edge_i, edge_t, xib, xtb, counts, N, E, nblkR, nbuk);

    k_s1<<<nbuk, 256, 0, stream>>>(counts, T, NBLK, nbuk);
    k_s2<<<1, 256, 0, stream>>>(T, Bb, rowptr, M, 2 * E, nbuk);
    k_part1<<<NBLK, 256, 0, stream>>>(edge_i, edge_t, counts, Bb, pairs,
                                      N, E, nblkR, nbuk);
    k_part2<<<nbuk, 256, 0, stream>>>(pairs, Bb, rowptr, col, M);

    {
        dim3 g((N * 16 + 255) / 256, 2);
        k_gather_mean<<<g, 256, 0, stream>>>(xib, xtb, rowptr, col, mi, mt, N);
    }

    k_final_mfma<<<(N + 255) / 256, 512, 0, stream>>>(
        mi, mt, x_user, Bp, bias, (float*)d_out, N);
}